// Round 2
// baseline (149.596 us; speedup 1.0000x reference)
//
#include <hip/hip_runtime.h>
#include <hip/hip_bf16.h>

#define RADIUS_F 1.3f
#define NSAMP 767
#define STEPF 0.01015625f   // RADIUS*2/COARSE/FINE/2
#define BATCH 1024

typedef __attribute__((ext_vector_type(8))) short short8;
typedef __attribute__((ext_vector_type(4))) float floatx4;
typedef __attribute__((ext_vector_type(4))) unsigned uintx4;
typedef __fp16 fp16x2 __attribute__((ext_vector_type(2)));

static __device__ __forceinline__ unsigned pkbf(float a, float b) {
    union { __hip_bfloat162 h; unsigned u; } cvt;
    cvt.h = __float22bfloat162_rn(make_float2(a, b));
    return cvt.u;
}
static __device__ __forceinline__ unsigned pkh(float a, float b) {
    union { fp16x2 h; unsigned u; } c;
    c.h = __builtin_amdgcn_cvt_pkrtz(a, b);
    return c.u;
}
static __device__ __forceinline__ float2 uph(unsigned u) {
    union { unsigned u; fp16x2 h; } c; c.u = u;
    return make_float2((float)c.h.x, (float)c.h.y);
}

// sum over the 4-lane coset {i, i^4, i^8, i^12} inside each row of 16,
// via DPP row rotates (VALU pipe, no LDS)
static __device__ __forceinline__ float coset4_sum(float p) {
    int q4 = __builtin_amdgcn_update_dpp(0, __float_as_int(p), 0x124, 0xf, 0xf, true); // row_ror:4
    p = p + __int_as_float(q4);
    int q8 = __builtin_amdgcn_update_dpp(0, __float_as_int(p), 0x128, 0xf, 0xf, true); // row_ror:8
    return p + __int_as_float(q8);
}

// launch_bounds (512,8): 8 waves/EU -> 4 blocks/CU -> 32 waves/CU
__launch_bounds__(512, 8)
__global__ void plenoxels_fwd(const float* __restrict__ rays_o,
                              const float* __restrict__ rays_d,
                              const float* __restrict__ grid,
                              const float* __restrict__ atoms,
                              float* __restrict__ out)
{
    // LDS: 4608 (B'', row stride 72: 2-way banks on bq ds_read_b128)
    //    + 12416 (Wt[f0][s], stride 776: conflict-free b128 reads in stage 2)
    //    + 12288 (pAct: activated {r,g,b,a} f32 per sample)
    //    + 3072  (clinL: per-sample cell index -> no shfl chains, no live clin regs)
    //    + 192   = 32576 B  (4 blocks/CU: 130 KB < 160 KB)
    __shared__ __align__(16) __hip_bfloat16 BpL[32 * 72];
    __shared__ __align__(16) unsigned WtU[4 * 776];
    __shared__ __align__(16) float pAct[768 * 4];
    __shared__ int clinL[768];
    __shared__ float wprodL[8];
    __shared__ float partL[8][5];

    const int tid  = threadIdx.x;
    const int ray  = blockIdx.x;
    const int lane = tid & 63;
    const int w    = tid >> 6;        // 8 waves
    const int m    = lane & 15;
    const int quad = lane >> 4;

    // ---- per-ray constants (block-uniform -> scalar path) ----
    const float ox = rays_o[ray * 3 + 0], oy = rays_o[ray * 3 + 1], oz = rays_o[ray * 3 + 2];
    const float dx = rays_d[ray * 3 + 0], dy = rays_d[ray * 3 + 1], dz = rays_d[ray * 3 + 2];

    float start, exitT;
    {
        float a0 = (RADIUS_F - ox) / dx, b0 = (-RADIUS_F - ox) / dx;
        float a1 = (RADIUS_F - oy) / dy, b1 = (-RADIUS_F - oy) / dy;
        float a2 = (RADIUS_F - oz) / dz, b2 = (-RADIUS_F - oz) / dz;
        start = fmaxf(fminf(a0, b0), fmaxf(fminf(a1, b1), fminf(a2, b2)));
        exitT = fminf(fmaxf(a0, b0), fminf(fmaxf(a1, b1), fmaxf(a2, b2)));
    }
    const float dnorm = sqrtf(dx * dx + dy * dy + dz * dz);
    const float dist = STEPF * dnorm;

    // ---- exit clipping: only ~256-445 of 767 samples are inside the AABB.
    // nAct is a CONSERVATIVE upper bound (margin +2 samples >> fp noise);
    // per-sample mask in geom() remains the authoritative correctness gate.
    int nAct;
    {
        float span = (exitT - start) / STEPF;          // may be inf/NaN
        if (span >= 0.f) nAct = (span < 765.f) ? ((int)span + 2) : NSAMP;
        else             nAct = (span < 0.f) ? 0 : NSAMP;   // NaN -> conservative full
    }
    const int seg = ((nAct + 127) >> 7) << 4;   // per-wave samples, mult of 16, 0..96
    const int nT  = seg >> 4;                    // tiles per wave, 0..6 (uniform in block)

    // geometry for one sample: packed W pairs -> Wt[f0][s], cell index -> clinL[s]
    auto geom = [&](int s) {
        float tr = start + (float)s * STEPF;
        float px = ox + tr * dx, py = oy + tr * dy, pz = oz + tr * dz;
        int mask = (px > -RADIUS_F) & (px < RADIUS_F) &
                   (py > -RADIUS_F) & (py < RADIUS_F) &
                   (pz > -RADIUS_F) & (pz < RADIUS_F) & (s < NSAMP);
        float maskf = mask ? 1.f : 0.f;
        const float sc = 1.0f / (2.0f * RADIUS_F);
        float qx = fminf(fmaxf((px + RADIUS_F) * sc, 0.f), 1.0f - 1e-6f);
        float qy = fminf(fmaxf((py + RADIUS_F) * sc, 0.f), 1.0f - 1e-6f);
        float qz = fminf(fmaxf((pz + RADIUS_F) * sc, 0.f), 1.0f - 1e-6f);
        float pcx = qx * 64.f, pcy = qy * 64.f, pcz = qz * 64.f;
        float cx = fminf(floorf(pcx), 63.f);
        float cy = fminf(floorf(pcy), 63.f);
        float cz = fminf(floorf(pcz), 63.f);
        float lx = pcx - cx, ly = pcy - cy, lz = pcz - cz;
        int clin = (((int)cx * 64) + (int)cy) * 64 + (int)cz;
        float xw0, xw1, yw0, yw1, zw0, zw1;
        {
            float u = lx * 2.f - 0.5f, fF = floorf(u), t = u - fF;
            xw0 = (fF < 0.f) ? 1.f : ((fF > 0.f) ? 0.f : 1.f - t);
            xw1 = (fF < 0.f) ? 0.f : ((fF > 0.f) ? 1.f : t);
        }
        {
            float u = ly * 2.f - 0.5f, fF = floorf(u), t = u - fF;
            yw0 = (fF < 0.f) ? 1.f : ((fF > 0.f) ? 0.f : 1.f - t);
            yw1 = (fF < 0.f) ? 0.f : ((fF > 0.f) ? 1.f : t);
        }
        {
            float u = lz * 2.f - 0.5f, fF = floorf(u), t = u - fF;
            zw0 = (fF < 0.f) ? 1.f : ((fF > 0.f) ? 0.f : 1.f - t);
            zw1 = (fF < 0.f) ? 0.f : ((fF > 0.f) ? 1.f : t);
        }
        xw0 *= maskf; xw1 *= maskf;          // fold mask: W=0 => sigma=0, rgb pre-act=0
        float g0 = yw0 * zw0, g1 = yw0 * zw1, g2 = yw1 * zw0, g3 = yw1 * zw1;
        WtU[       s] = pkh(xw0 * g0, xw1 * g0);
        WtU[ 776 + s] = pkh(xw0 * g1, xw1 * g1);
        WtU[1552 + s] = pkh(xw0 * g2, xw1 * g2);
        WtU[2328 + s] = pkh(xw0 * g3, xw1 * g3);
        clinL[s] = clin;
    };

    // ---- wave-local geometry over [w*seg, (w+1)*seg) — all waves balanced ----
    if (lane < seg)      geom(w * seg + lane);
    if (lane + 64 < seg) geom(w * seg + 64 + lane);

    // ---- tile-0 coeff gather issues now; latency hides under B'' build ----
    // (clinL read is wave-local: same wave wrote it; compiler inserts lgkmcnt)
    const float4* g4 = (const float4*)grid;
    float4 cv0 = {0,0,0,0}, cv1 = {0,0,0,0}, cv2 = {0,0,0,0}, cv3 = {0,0,0,0};
    if (nT > 0) {
        int clinC = clinL[w * seg + m];
        const float4* gp = g4 + (clinC << 4) + (quad << 2);
        cv0 = gp[0]; cv1 = gp[1]; cv2 = gp[2]; cv3 = gp[3];
    }

    // ---- build B'': one (f,a) entry per thread; cols 4f+c (c<3 SH-contracted, c=3 sigma) ----
    {
        float shm[9];
        float inv = 1.0f / dnorm;
        float nx = dx * inv, ny = dy * inv, nz = dz * inv;
        shm[0] = 0.28209479177387814f;
        shm[1] = -0.4886025119029199f * ny;
        shm[2] = 0.4886025119029199f * nz;
        shm[3] = -0.4886025119029199f * nx;
        shm[4] = 1.0925484305920792f * nx * ny;
        shm[5] = -1.0925484305920792f * ny * nz;
        shm[6] = 0.31539156525252005f * (2.f * nz * nz - nx * nx - ny * ny);
        shm[7] = -1.0925484305920792f * nx * nz;
        shm[8] = 0.5462742152960396f * (nx * nx - ny * ny);

        const float* base = atoms + tid * 28;
        float4 v0 = *(const float4*)(base);
        float4 v1 = *(const float4*)(base + 4);
        float4 v2 = *(const float4*)(base + 8);
        float4 v3 = *(const float4*)(base + 12);
        float4 v4 = *(const float4*)(base + 16);
        float4 v5 = *(const float4*)(base + 20);
        float4 v6 = *(const float4*)(base + 24);

        float s0 = v0.x*shm[0] + v0.y*shm[1] + v0.z*shm[2] + v0.w*shm[3]
                 + v1.x*shm[4] + v1.y*shm[5] + v1.z*shm[6] + v1.w*shm[7] + v2.x*shm[8];
        float s1 = v2.y*shm[0] + v2.z*shm[1] + v2.w*shm[2] + v3.x*shm[3]
                 + v3.y*shm[4] + v3.z*shm[5] + v3.w*shm[6] + v4.x*shm[7] + v4.y*shm[8];
        float s2 = v4.z*shm[0] + v4.w*shm[1] + v5.x*shm[2] + v5.y*shm[3]
                 + v5.z*shm[4] + v5.w*shm[5] + v6.x*shm[6] + v6.y*shm[7] + v6.z*shm[8];

        int f = tid >> 6, a = tid & 63;
        int cb = (f << 2) * 72 + a;          // row (4f+c), stride 72
        BpL[cb]        = __float2bfloat16(s0);
        BpL[cb + 72]   = __float2bfloat16(s1);
        BpL[cb + 144]  = __float2bfloat16(s2);
        BpL[cb + 216]  = __float2bfloat16(v6.w);   // sigma column
    }
    __syncthreads();

    // ---- B-fragments (tile-invariant); padded stride -> 2-way banks (free) ----
    short8 bq00, bq01, bq10, bq11;
    {
        const short* bs = (const short*)BpL;
        const short* p0 = bs + m * 72 + (quad << 4);
        bq00 = *(const short8*)(p0);
        bq01 = *(const short8*)(p0 + 8);
        const short* p1 = bs + (16 + m) * 72 + (quad << 4);
        bq10 = *(const short8*)(p1);
        bq11 = *(const short8*)(p1 + 8);
    }

    float* out_rgb   = out;
    float* out_alpha = out + BATCH * 3;
    float* out_depth = out + BATCH * 3 + BATCH * NSAMP;
    const int f0 = m >> 2;

    // ---- main loop: compile-time 6 bodies, uniform break at nT (3-4 typical) ----
    #pragma unroll
    for (int t = 0; t < 6; ++t) {
        if (t >= nT) break;

        // A-frags: raw coeff, bf16
        union { unsigned u[4]; short8 s; } a0p, a1p;
        a0p.u[0] = pkbf(cv0.x, cv0.y); a0p.u[1] = pkbf(cv0.z, cv0.w);
        a0p.u[2] = pkbf(cv1.x, cv1.y); a0p.u[3] = pkbf(cv1.z, cv1.w);
        a1p.u[0] = pkbf(cv2.x, cv2.y); a1p.u[1] = pkbf(cv2.z, cv2.w);
        a1p.u[2] = pkbf(cv3.x, cv3.y); a1p.u[3] = pkbf(cv3.z, cv3.w);

        // prefetch next tile's coeff gather (clin from LDS, wave-local)
        if (t + 1 < nT) {
            int clinC = clinL[w * seg + ((t + 1) << 4) + m];
            const float4* gp = g4 + (clinC << 4) + (quad << 2);
            cv0 = gp[0]; cv1 = gp[1]; cv2 = gp[2]; cv3 = gp[3];
        }

        // stage 1: proj = Coeff(16x64) x B''(64x32)
        floatx4 acc0 = {0.f, 0.f, 0.f, 0.f};
        floatx4 acc1 = {0.f, 0.f, 0.f, 0.f};
        acc0 = __builtin_amdgcn_mfma_f32_16x16x32_bf16(a0p.s, bq00, acc0, 0, 0, 0);
        acc0 = __builtin_amdgcn_mfma_f32_16x16x32_bf16(a1p.s, bq01, acc0, 0, 0, 0);
        acc1 = __builtin_amdgcn_mfma_f32_16x16x32_bf16(a0p.s, bq10, acc1, 0, 0, 0);
        acc1 = __builtin_amdgcn_mfma_f32_16x16x32_bf16(a1p.s, bq11, acc1, 0, 0, 0);

        // stage 2: p[s][c] = sum_f W[s][f]*proj[s][4f+c]; activations fused here
        int sb = w * seg + (t << 4) + (quad << 2);
        union { uintx4 v; unsigned u[4]; } wt;
        wt.v = *(const uintx4*)&WtU[f0 * 776 + sb];   // one ds_read_b128, 2-way banks
        #pragma unroll
        for (int r = 0; r < 4; ++r) {
            float2 wab = uph(wt.u[r]);
            float p = wab.x * acc0[r] + wab.y * acc1[r];
            p = coset4_sum(p);                        // reduce over f; c = m&3
            if (m < 4) {                              // lane m holds channel c=m
                float e = __expf((m == 3) ? (-fmaxf(p, 0.f) * dist) : -p);
                float v = (m == 3) ? (1.f - e) : (1.f / (1.f + e));
                pAct[((sb + r) << 2) + m] = v;        // {r,g,b,a}
            }
        }
    }

    __syncthreads();

    // ---- phase 2: transmittance scan + composite (transcendental-free) ----
    {
        const int sLim = seg << 3;          // samples with pAct written; beyond -> a=0
        const bool act = (tid < 384);
        const int s0 = tid * 2;             // 0..766
        float a0 = 0.f, a1 = 0.f;
        float r0 = 0.f, g0c = 0.f, b0c = 0.f, r1 = 0.f, g1c = 0.f, b1c = 0.f;
        if (act) {
            if (s0 < sLim) {
                float4 q = *(const float4*)&pAct[s0 << 2];
                r0 = q.x; g0c = q.y; b0c = q.z; a0 = q.w;
            }
            if (s0 + 1 < sLim) {
                float4 q = *(const float4*)&pAct[(s0 + 1) << 2];
                r1 = q.x; g1c = q.y; b1c = q.z; a1 = q.w;
            }
            // coalesced alpha store (zeros beyond the clipped range included)
            out_alpha[ray * NSAMP + s0] = a0;
            if (s0 + 1 < NSAMP) out_alpha[ray * NSAMP + s0 + 1] = a1;
        }
        float pr = (1.f - a0 + 1e-10f) * (1.f - a1 + 1e-10f);

        // intra-wave inclusive multiplicative scan over pair products
        float incl = pr;
        #pragma unroll
        for (int off = 1; off < 64; off <<= 1) {
            float v = __shfl_up(incl, off, 64);
            if (lane >= off) incl *= v;
        }
        if (lane == 63) wprodL[w] = incl;
        __syncthreads();

        float base = 1.f;
        #pragma unroll
        for (int ww = 0; ww < 5; ++ww)
            if (w > ww) base *= wprodL[ww];
        float excl = __shfl_up(incl, 1, 64);
        if (lane == 0) excl = 1.f;
        float trans = base * excl;

        float c0 = 0.f, c1 = 0.f, c2 = 0.f, accw = 0.f, dep = 0.f;
        if (act) {
            float w0 = a0 * trans;
            c0 += w0 * r0; c1 += w0 * g0c; c2 += w0 * b0c;
            accw += w0;
            dep += w0 * (start + (float)s0 * STEPF);
            trans *= (1.f - a0 + 1e-10f);
            float w1 = a1 * trans;
            c0 += w1 * r1; c1 += w1 * g1c; c2 += w1 * b1c;
            accw += w1;
            dep += w1 * (start + (float)(s0 + 1) * STEPF);
        }
        #pragma unroll
        for (int off = 1; off < 64; off <<= 1) {
            c0   += __shfl_xor(c0, off, 64);
            c1   += __shfl_xor(c1, off, 64);
            c2   += __shfl_xor(c2, off, 64);
            accw += __shfl_xor(accw, off, 64);
            dep  += __shfl_xor(dep, off, 64);
        }
        if (lane == 0) {
            partL[w][0] = c0; partL[w][1] = c1; partL[w][2] = c2;
            partL[w][3] = accw; partL[w][4] = dep;
        }
        __syncthreads();
        if (tid == 0) {
            float C0 = 0.f, C1 = 0.f, C2 = 0.f, AC = 0.f, DP = 0.f;
            #pragma unroll
            for (int ww = 0; ww < 6; ++ww) {   // act threads live in waves 0..5
                C0 += partL[ww][0]; C1 += partL[ww][1]; C2 += partL[ww][2];
                AC += partL[ww][3]; DP += partL[ww][4];
            }
            float bg = 1.f - AC;
            out_rgb[ray * 3 + 0] = C0 + bg;
            out_rgb[ray * 3 + 1] = C1 + bg;
            out_rgb[ray * 3 + 2] = C2 + bg;
            out_depth[ray] = DP;
        }
    }
}

extern "C" void kernel_launch(void* const* d_in, const int* in_sizes, int n_in,
                              void* d_out, int out_size, void* d_ws, size_t ws_size,
                              hipStream_t stream) {
    const float* rays_o = (const float*)d_in[0];
    const float* rays_d = (const float*)d_in[1];
    const float* grid   = (const float*)d_in[2];
    const float* atoms  = (const float*)d_in[3];
    float* out = (float*)d_out;
    hipLaunchKernelGGL(plenoxels_fwd, dim3(BATCH), dim3(512), 0, stream,
                       rays_o, rays_d, grid, atoms, out);
}

// Round 3
// 112.360 us; speedup vs baseline: 1.3314x; 1.3314x over previous
//
#include <hip/hip_runtime.h>
#include <hip/hip_bf16.h>

#define RADIUS_F 1.3f
#define NSAMP 767
#define STEPF 0.01015625f   // RADIUS*2/COARSE/FINE/2
#define BATCH 1024

typedef __attribute__((ext_vector_type(8))) short short8;
typedef __attribute__((ext_vector_type(4))) float floatx4;
typedef __attribute__((ext_vector_type(4))) unsigned uintx4;
typedef __fp16 fp16x2 __attribute__((ext_vector_type(2)));

static __device__ __forceinline__ unsigned pkbf(float a, float b) {
    union { __hip_bfloat162 h; unsigned u; } cvt;
    cvt.h = __float22bfloat162_rn(make_float2(a, b));
    return cvt.u;
}
static __device__ __forceinline__ unsigned pkh(float a, float b) {
    union { fp16x2 h; unsigned u; } c;
    c.h = __builtin_amdgcn_cvt_pkrtz(a, b);
    return c.u;
}
static __device__ __forceinline__ float2 uph(unsigned u) {
    union { unsigned u; fp16x2 h; } c; c.u = u;
    return make_float2((float)c.h.x, (float)c.h.y);
}

// sum over the 4-lane coset {i, i^4, i^8, i^12} inside each row of 16,
// via DPP row rotates (VALU pipe, no LDS)
static __device__ __forceinline__ float coset4_sum(float p) {
    int q4 = __builtin_amdgcn_update_dpp(0, __float_as_int(p), 0x124, 0xf, 0xf, true); // row_ror:4
    p = p + __int_as_float(q4);
    int q8 = __builtin_amdgcn_update_dpp(0, __float_as_int(p), 0x128, 0xf, 0xf, true); // row_ror:8
    return p + __int_as_float(q8);
}

// launch_bounds (512,4): 4 waves/EU -> 2 blocks/CU, VGPR cap 128 (was 64 at (512,8):
// round-2 counters showed ~169 MB/dispatch of scratch writes = whole working set
// spilled under the 64-reg cap; measured occupancy was only ~16 waves/CU anyway)
__launch_bounds__(512, 4)
__global__ void plenoxels_fwd(const float* __restrict__ rays_o,
                              const float* __restrict__ rays_d,
                              const float* __restrict__ grid,
                              const float* __restrict__ atoms,
                              float* __restrict__ out)
{
    // LDS: 4608 (B'', row stride 72: 2-way banks on bq ds_read_b128)
    //    + 12416 (Wt[f0][s], stride 776: conflict-free b128 reads in stage 2)
    //    + 12288 (pAct: activated {r,g,b,a} f32 per sample)
    //    + 3072  (clinL: per-sample cell index)
    //    + 192   = 32576 B  (2 blocks/CU: 65 KB < 160 KB)
    __shared__ __align__(16) __hip_bfloat16 BpL[32 * 72];
    __shared__ __align__(16) unsigned WtU[4 * 776];
    __shared__ __align__(16) float pAct[768 * 4];
    __shared__ int clinL[768];
    __shared__ float wprodL[8];
    __shared__ float partL[8][5];

    const int tid  = threadIdx.x;
    const int ray  = blockIdx.x;
    const int lane = tid & 63;
    const int w    = tid >> 6;        // 8 waves
    const int m    = lane & 15;
    const int quad = lane >> 4;

    // ---- per-ray constants (block-uniform -> scalar path) ----
    const float ox = rays_o[ray * 3 + 0], oy = rays_o[ray * 3 + 1], oz = rays_o[ray * 3 + 2];
    const float dx = rays_d[ray * 3 + 0], dy = rays_d[ray * 3 + 1], dz = rays_d[ray * 3 + 2];

    float start, exitT;
    {
        float a0 = (RADIUS_F - ox) / dx, b0 = (-RADIUS_F - ox) / dx;
        float a1 = (RADIUS_F - oy) / dy, b1 = (-RADIUS_F - oy) / dy;
        float a2 = (RADIUS_F - oz) / dz, b2 = (-RADIUS_F - oz) / dz;
        start = fmaxf(fminf(a0, b0), fmaxf(fminf(a1, b1), fminf(a2, b2)));
        exitT = fminf(fmaxf(a0, b0), fminf(fmaxf(a1, b1), fmaxf(a2, b2)));
    }
    const float dnorm = sqrtf(dx * dx + dy * dy + dz * dz);
    const float dist = STEPF * dnorm;

    // ---- exit clipping: only ~256-445 of 767 samples are inside the AABB.
    // nAct is a CONSERVATIVE upper bound (margin +2 samples >> fp noise);
    // per-sample mask in geom() remains the authoritative correctness gate.
    int nAct;
    {
        float span = (exitT - start) / STEPF;          // may be inf/NaN
        if (span >= 0.f) nAct = (span < 765.f) ? ((int)span + 2) : NSAMP;
        else             nAct = (span < 0.f) ? 0 : NSAMP;   // NaN -> conservative full
    }
    const int seg = ((nAct + 127) >> 7) << 4;   // per-wave samples, mult of 16, 0..96
    const int nT  = seg >> 4;                    // tiles per wave, 0..6 (uniform in block)

    // geometry for one sample: packed W pairs -> Wt[f0][s], cell index -> clinL[s]
    auto geom = [&](int s) {
        float tr = start + (float)s * STEPF;
        float px = ox + tr * dx, py = oy + tr * dy, pz = oz + tr * dz;
        int mask = (px > -RADIUS_F) & (px < RADIUS_F) &
                   (py > -RADIUS_F) & (py < RADIUS_F) &
                   (pz > -RADIUS_F) & (pz < RADIUS_F) & (s < NSAMP);
        float maskf = mask ? 1.f : 0.f;
        const float sc = 1.0f / (2.0f * RADIUS_F);
        float qx = fminf(fmaxf((px + RADIUS_F) * sc, 0.f), 1.0f - 1e-6f);
        float qy = fminf(fmaxf((py + RADIUS_F) * sc, 0.f), 1.0f - 1e-6f);
        float qz = fminf(fmaxf((pz + RADIUS_F) * sc, 0.f), 1.0f - 1e-6f);
        float pcx = qx * 64.f, pcy = qy * 64.f, pcz = qz * 64.f;
        float cx = fminf(floorf(pcx), 63.f);
        float cy = fminf(floorf(pcy), 63.f);
        float cz = fminf(floorf(pcz), 63.f);
        float lx = pcx - cx, ly = pcy - cy, lz = pcz - cz;
        int clin = (((int)cx * 64) + (int)cy) * 64 + (int)cz;
        float xw0, xw1, yw0, yw1, zw0, zw1;
        {
            float u = lx * 2.f - 0.5f, fF = floorf(u), t = u - fF;
            xw0 = (fF < 0.f) ? 1.f : ((fF > 0.f) ? 0.f : 1.f - t);
            xw1 = (fF < 0.f) ? 0.f : ((fF > 0.f) ? 1.f : t);
        }
        {
            float u = ly * 2.f - 0.5f, fF = floorf(u), t = u - fF;
            yw0 = (fF < 0.f) ? 1.f : ((fF > 0.f) ? 0.f : 1.f - t);
            yw1 = (fF < 0.f) ? 0.f : ((fF > 0.f) ? 1.f : t);
        }
        {
            float u = lz * 2.f - 0.5f, fF = floorf(u), t = u - fF;
            zw0 = (fF < 0.f) ? 1.f : ((fF > 0.f) ? 0.f : 1.f - t);
            zw1 = (fF < 0.f) ? 0.f : ((fF > 0.f) ? 1.f : t);
        }
        xw0 *= maskf; xw1 *= maskf;          // fold mask: W=0 => sigma=0, rgb pre-act=0
        float g0 = yw0 * zw0, g1 = yw0 * zw1, g2 = yw1 * zw0, g3 = yw1 * zw1;
        WtU[       s] = pkh(xw0 * g0, xw1 * g0);
        WtU[ 776 + s] = pkh(xw0 * g1, xw1 * g1);
        WtU[1552 + s] = pkh(xw0 * g2, xw1 * g2);
        WtU[2328 + s] = pkh(xw0 * g3, xw1 * g3);
        clinL[s] = clin;
    };

    // ---- wave-local geometry over [w*seg, (w+1)*seg) — all waves balanced ----
    if (lane < seg)      geom(w * seg + lane);
    if (lane + 64 < seg) geom(w * seg + 64 + lane);

    // ---- tile-0 coeff gather issues now; latency hides under B'' build ----
    // (clinL read is wave-local: same wave wrote it; compiler inserts lgkmcnt)
    const float4* g4 = (const float4*)grid;
    float4 cv0 = {0,0,0,0}, cv1 = {0,0,0,0}, cv2 = {0,0,0,0}, cv3 = {0,0,0,0};
    if (nT > 0) {
        int clinC = clinL[w * seg + m];
        const float4* gp = g4 + (clinC << 4) + (quad << 2);
        cv0 = gp[0]; cv1 = gp[1]; cv2 = gp[2]; cv3 = gp[3];
    }

    // ---- build B'': one (f,a) entry per thread; cols 4f+c (c<3 SH-contracted, c=3 sigma) ----
    {
        float shm[9];
        float inv = 1.0f / dnorm;
        float nx = dx * inv, ny = dy * inv, nz = dz * inv;
        shm[0] = 0.28209479177387814f;
        shm[1] = -0.4886025119029199f * ny;
        shm[2] = 0.4886025119029199f * nz;
        shm[3] = -0.4886025119029199f * nx;
        shm[4] = 1.0925484305920792f * nx * ny;
        shm[5] = -1.0925484305920792f * ny * nz;
        shm[6] = 0.31539156525252005f * (2.f * nz * nz - nx * nx - ny * ny);
        shm[7] = -1.0925484305920792f * nx * nz;
        shm[8] = 0.5462742152960396f * (nx * nx - ny * ny);

        const float* base = atoms + tid * 28;
        float4 v0 = *(const float4*)(base);
        float4 v1 = *(const float4*)(base + 4);
        float4 v2 = *(const float4*)(base + 8);
        float4 v3 = *(const float4*)(base + 12);
        float4 v4 = *(const float4*)(base + 16);
        float4 v5 = *(const float4*)(base + 20);
        float4 v6 = *(const float4*)(base + 24);

        float s0 = v0.x*shm[0] + v0.y*shm[1] + v0.z*shm[2] + v0.w*shm[3]
                 + v1.x*shm[4] + v1.y*shm[5] + v1.z*shm[6] + v1.w*shm[7] + v2.x*shm[8];
        float s1 = v2.y*shm[0] + v2.z*shm[1] + v2.w*shm[2] + v3.x*shm[3]
                 + v3.y*shm[4] + v3.z*shm[5] + v3.w*shm[6] + v4.x*shm[7] + v4.y*shm[8];
        float s2 = v4.z*shm[0] + v4.w*shm[1] + v5.x*shm[2] + v5.y*shm[3]
                 + v5.z*shm[4] + v5.w*shm[5] + v6.x*shm[6] + v6.y*shm[7] + v6.z*shm[8];

        int f = tid >> 6, a = tid & 63;
        int cb = (f << 2) * 72 + a;          // row (4f+c), stride 72
        BpL[cb]        = __float2bfloat16(s0);
        BpL[cb + 72]   = __float2bfloat16(s1);
        BpL[cb + 144]  = __float2bfloat16(s2);
        BpL[cb + 216]  = __float2bfloat16(v6.w);   // sigma column
    }
    __syncthreads();

    // ---- B-fragments (tile-invariant); padded stride -> 2-way banks (free) ----
    short8 bq00, bq01, bq10, bq11;
    {
        const short* bs = (const short*)BpL;
        const short* p0 = bs + m * 72 + (quad << 4);
        bq00 = *(const short8*)(p0);
        bq01 = *(const short8*)(p0 + 8);
        const short* p1 = bs + (16 + m) * 72 + (quad << 4);
        bq10 = *(const short8*)(p1);
        bq11 = *(const short8*)(p1 + 8);
    }

    float* out_rgb   = out;
    float* out_alpha = out + BATCH * 3;
    float* out_depth = out + BATCH * 3 + BATCH * NSAMP;
    const int f0 = m >> 2;

    // ---- main loop: compile-time 6 bodies, uniform break at nT (2-4 typical) ----
    #pragma unroll
    for (int t = 0; t < 6; ++t) {
        if (t >= nT) break;

        // A-frags: raw coeff, bf16
        union { unsigned u[4]; short8 s; } a0p, a1p;
        a0p.u[0] = pkbf(cv0.x, cv0.y); a0p.u[1] = pkbf(cv0.z, cv0.w);
        a0p.u[2] = pkbf(cv1.x, cv1.y); a0p.u[3] = pkbf(cv1.z, cv1.w);
        a1p.u[0] = pkbf(cv2.x, cv2.y); a1p.u[1] = pkbf(cv2.z, cv2.w);
        a1p.u[2] = pkbf(cv3.x, cv3.y); a1p.u[3] = pkbf(cv3.z, cv3.w);

        // prefetch next tile's coeff gather (clin from LDS, wave-local)
        if (t + 1 < nT) {
            int clinC = clinL[w * seg + ((t + 1) << 4) + m];
            const float4* gp = g4 + (clinC << 4) + (quad << 2);
            cv0 = gp[0]; cv1 = gp[1]; cv2 = gp[2]; cv3 = gp[3];
        }

        // stage 1: proj = Coeff(16x64) x B''(64x32)
        floatx4 acc0 = {0.f, 0.f, 0.f, 0.f};
        floatx4 acc1 = {0.f, 0.f, 0.f, 0.f};
        acc0 = __builtin_amdgcn_mfma_f32_16x16x32_bf16(a0p.s, bq00, acc0, 0, 0, 0);
        acc0 = __builtin_amdgcn_mfma_f32_16x16x32_bf16(a1p.s, bq01, acc0, 0, 0, 0);
        acc1 = __builtin_amdgcn_mfma_f32_16x16x32_bf16(a0p.s, bq10, acc1, 0, 0, 0);
        acc1 = __builtin_amdgcn_mfma_f32_16x16x32_bf16(a1p.s, bq11, acc1, 0, 0, 0);

        // stage 2: p[s][c] = sum_f W[s][f]*proj[s][4f+c]; activations fused here
        int sb = w * seg + (t << 4) + (quad << 2);
        union { uintx4 v; unsigned u[4]; } wt;
        wt.v = *(const uintx4*)&WtU[f0 * 776 + sb];   // one ds_read_b128, 2-way banks
        #pragma unroll
        for (int r = 0; r < 4; ++r) {
            float2 wab = uph(wt.u[r]);
            float p = wab.x * acc0[r] + wab.y * acc1[r];
            p = coset4_sum(p);                        // reduce over f; c = m&3
            if (m < 4) {                              // lane m holds channel c=m
                float e = __expf((m == 3) ? (-fmaxf(p, 0.f) * dist) : -p);
                float v = (m == 3) ? (1.f - e) : (1.f / (1.f + e));
                pAct[((sb + r) << 2) + m] = v;        // {r,g,b,a}
            }
        }
    }

    __syncthreads();

    // ---- phase 2: transmittance scan + composite (transcendental-free) ----
    {
        const int sLim = seg << 3;          // samples with pAct written; beyond -> a=0
        const bool act = (tid < 384);
        const int s0 = tid * 2;             // 0..766
        float a0 = 0.f, a1 = 0.f;
        float r0 = 0.f, g0c = 0.f, b0c = 0.f, r1 = 0.f, g1c = 0.f, b1c = 0.f;
        if (act) {
            if (s0 < sLim) {
                float4 q = *(const float4*)&pAct[s0 << 2];
                r0 = q.x; g0c = q.y; b0c = q.z; a0 = q.w;
            }
            if (s0 + 1 < sLim) {
                float4 q = *(const float4*)&pAct[(s0 + 1) << 2];
                r1 = q.x; g1c = q.y; b1c = q.z; a1 = q.w;
            }
            // coalesced alpha store (zeros beyond the clipped range included)
            out_alpha[ray * NSAMP + s0] = a0;
            if (s0 + 1 < NSAMP) out_alpha[ray * NSAMP + s0 + 1] = a1;
        }
        float pr = (1.f - a0 + 1e-10f) * (1.f - a1 + 1e-10f);

        // intra-wave inclusive multiplicative scan over pair products
        float incl = pr;
        #pragma unroll
        for (int off = 1; off < 64; off <<= 1) {
            float v = __shfl_up(incl, off, 64);
            if (lane >= off) incl *= v;
        }
        if (lane == 63) wprodL[w] = incl;
        __syncthreads();

        float base = 1.f;
        #pragma unroll
        for (int ww = 0; ww < 5; ++ww)
            if (w > ww) base *= wprodL[ww];
        float excl = __shfl_up(incl, 1, 64);
        if (lane == 0) excl = 1.f;
        float trans = base * excl;

        float c0 = 0.f, c1 = 0.f, c2 = 0.f, accw = 0.f, dep = 0.f;
        if (act) {
            float w0 = a0 * trans;
            c0 += w0 * r0; c1 += w0 * g0c; c2 += w0 * b0c;
            accw += w0;
            dep += w0 * (start + (float)s0 * STEPF);
            trans *= (1.f - a0 + 1e-10f);
            float w1 = a1 * trans;
            c0 += w1 * r1; c1 += w1 * g1c; c2 += w1 * b1c;
            accw += w1;
            dep += w1 * (start + (float)(s0 + 1) * STEPF);
        }
        #pragma unroll
        for (int off = 1; off < 64; off <<= 1) {
            c0   += __shfl_xor(c0, off, 64);
            c1   += __shfl_xor(c1, off, 64);
            c2   += __shfl_xor(c2, off, 64);
            accw += __shfl_xor(accw, off, 64);
            dep  += __shfl_xor(dep, off, 64);
        }
        if (lane == 0) {
            partL[w][0] = c0; partL[w][1] = c1; partL[w][2] = c2;
            partL[w][3] = accw; partL[w][4] = dep;
        }
        __syncthreads();
        if (tid == 0) {
            float C0 = 0.f, C1 = 0.f, C2 = 0.f, AC = 0.f, DP = 0.f;
            #pragma unroll
            for (int ww = 0; ww < 6; ++ww) {   // act threads live in waves 0..5
                C0 += partL[ww][0]; C1 += partL[ww][1]; C2 += partL[ww][2];
                AC += partL[ww][3]; DP += partL[ww][4];
            }
            float bg = 1.f - AC;
            out_rgb[ray * 3 + 0] = C0 + bg;
            out_rgb[ray * 3 + 1] = C1 + bg;
            out_rgb[ray * 3 + 2] = C2 + bg;
            out_depth[ray] = DP;
        }
    }
}

extern "C" void kernel_launch(void* const* d_in, const int* in_sizes, int n_in,
                              void* d_out, int out_size, void* d_ws, size_t ws_size,
                              hipStream_t stream) {
    const float* rays_o = (const float*)d_in[0];
    const float* rays_d = (const float*)d_in[1];
    const float* grid   = (const float*)d_in[2];
    const float* atoms  = (const float*)d_in[3];
    float* out = (float*)d_out;
    hipLaunchKernelGGL(plenoxels_fwd, dim3(BATCH), dim3(512), 0, stream,
                       rays_o, rays_d, grid, atoms, out);
}

// Round 4
// 111.942 us; speedup vs baseline: 1.3364x; 1.0037x over previous
//
#include <hip/hip_runtime.h>
#include <hip/hip_bf16.h>

#define RADIUS_F 1.3f
#define NSAMP 767
#define STEPF 0.01015625f   // RADIUS*2/COARSE/FINE/2
#define BATCH 1024

typedef __attribute__((ext_vector_type(8))) short short8;
typedef __attribute__((ext_vector_type(4))) float floatx4;
typedef __attribute__((ext_vector_type(4))) unsigned uintx4;
typedef __fp16 fp16x2 __attribute__((ext_vector_type(2)));

static __device__ __forceinline__ unsigned pkbf(float a, float b) {
    union { __hip_bfloat162 h; unsigned u; } cvt;
    cvt.h = __float22bfloat162_rn(make_float2(a, b));
    return cvt.u;
}
static __device__ __forceinline__ unsigned pkh(float a, float b) {
    union { fp16x2 h; unsigned u; } c;
    c.h = __builtin_amdgcn_cvt_pkrtz(a, b);
    return c.u;
}
static __device__ __forceinline__ float2 uph(unsigned u) {
    union { unsigned u; fp16x2 h; } c; c.u = u;
    return make_float2((float)c.h.x, (float)c.h.y);
}

// sum over the 4-lane coset {i, i^4, i^8, i^12} inside each row of 16,
// via DPP row rotates (VALU pipe, no LDS)
static __device__ __forceinline__ float coset4_sum(float p) {
    int q4 = __builtin_amdgcn_update_dpp(0, __float_as_int(p), 0x124, 0xf, 0xf, true); // row_ror:4
    p = p + __int_as_float(q4);
    int q8 = __builtin_amdgcn_update_dpp(0, __float_as_int(p), 0x128, 0xf, 0xf, true); // row_ror:8
    return p + __int_as_float(q8);
}

// launch_bounds (512,6): VGPR cap 85, 6 waves/EU -> 3 blocks/CU (24 waves/CU).
// History: (512,8) = 64-reg cap -> catastrophic spill (round 2: 169 MB scratch
// writes/dispatch); (512,4) = 128-reg cap, no spill, but only 2 blocks/CU and
// the kernel is latency-bound (VALUBusy 18%, ~75% stall). Live set ~70-85 regs
// should fit the 85 cap; +50% resident waves for stall overlap.
__launch_bounds__(512, 6)
__global__ void plenoxels_fwd(const float* __restrict__ rays_o,
                              const float* __restrict__ rays_d,
                              const float* __restrict__ grid,
                              const float* __restrict__ atoms,
                              float* __restrict__ out)
{
    // LDS: 4608 (B'', row stride 72: 2-way banks on bq ds_read_b128)
    //    + 12416 (Wt[f0][s], stride 776: conflict-free b128 reads in stage 2)
    //    + 12288 (pAct: activated {r,g,b,a} f32 per sample)
    //    + 3072  (clinL: per-sample cell index)
    //    + 192   = 32576 B  (3 blocks/CU: 98 KB < 160 KB)
    __shared__ __align__(16) __hip_bfloat16 BpL[32 * 72];
    __shared__ __align__(16) unsigned WtU[4 * 776];
    __shared__ __align__(16) float pAct[768 * 4];
    __shared__ int clinL[768];
    __shared__ float wprodL[8];
    __shared__ float partL[8][5];

    const int tid  = threadIdx.x;
    const int ray  = blockIdx.x;
    const int lane = tid & 63;
    const int w    = tid >> 6;        // 8 waves
    const int m    = lane & 15;
    const int quad = lane >> 4;

    // ---- per-ray constants (block-uniform -> scalar path) ----
    const float ox = rays_o[ray * 3 + 0], oy = rays_o[ray * 3 + 1], oz = rays_o[ray * 3 + 2];
    const float dx = rays_d[ray * 3 + 0], dy = rays_d[ray * 3 + 1], dz = rays_d[ray * 3 + 2];

    float start, exitT;
    {
        float a0 = (RADIUS_F - ox) / dx, b0 = (-RADIUS_F - ox) / dx;
        float a1 = (RADIUS_F - oy) / dy, b1 = (-RADIUS_F - oy) / dy;
        float a2 = (RADIUS_F - oz) / dz, b2 = (-RADIUS_F - oz) / dz;
        start = fmaxf(fminf(a0, b0), fmaxf(fminf(a1, b1), fminf(a2, b2)));
        exitT = fminf(fmaxf(a0, b0), fminf(fmaxf(a1, b1), fmaxf(a2, b2)));
    }
    const float dnorm = sqrtf(dx * dx + dy * dy + dz * dz);
    const float dist = STEPF * dnorm;

    // ---- exit clipping: only ~256-445 of 767 samples are inside the AABB.
    // nAct is a CONSERVATIVE upper bound (margin +2 samples >> fp noise);
    // per-sample mask in geom() remains the authoritative correctness gate.
    int nAct;
    {
        float span = (exitT - start) / STEPF;          // may be inf/NaN
        if (span >= 0.f) nAct = (span < 765.f) ? ((int)span + 2) : NSAMP;
        else             nAct = (span < 0.f) ? 0 : NSAMP;   // NaN -> conservative full
    }
    const int seg = ((nAct + 127) >> 7) << 4;   // per-wave samples, mult of 16, 0..96
    const int nT  = seg >> 4;                    // tiles per wave, 0..6 (uniform in block)

    // geometry for one sample: packed W pairs -> Wt[f0][s], cell index -> clinL[s]
    auto geom = [&](int s) {
        float tr = start + (float)s * STEPF;
        float px = ox + tr * dx, py = oy + tr * dy, pz = oz + tr * dz;
        int mask = (px > -RADIUS_F) & (px < RADIUS_F) &
                   (py > -RADIUS_F) & (py < RADIUS_F) &
                   (pz > -RADIUS_F) & (pz < RADIUS_F) & (s < NSAMP);
        float maskf = mask ? 1.f : 0.f;
        const float sc = 1.0f / (2.0f * RADIUS_F);
        float qx = fminf(fmaxf((px + RADIUS_F) * sc, 0.f), 1.0f - 1e-6f);
        float qy = fminf(fmaxf((py + RADIUS_F) * sc, 0.f), 1.0f - 1e-6f);
        float qz = fminf(fmaxf((pz + RADIUS_F) * sc, 0.f), 1.0f - 1e-6f);
        float pcx = qx * 64.f, pcy = qy * 64.f, pcz = qz * 64.f;
        float cx = fminf(floorf(pcx), 63.f);
        float cy = fminf(floorf(pcy), 63.f);
        float cz = fminf(floorf(pcz), 63.f);
        float lx = pcx - cx, ly = pcy - cy, lz = pcz - cz;
        int clin = (((int)cx * 64) + (int)cy) * 64 + (int)cz;
        float xw0, xw1, yw0, yw1, zw0, zw1;
        {
            float u = lx * 2.f - 0.5f, fF = floorf(u), t = u - fF;
            xw0 = (fF < 0.f) ? 1.f : ((fF > 0.f) ? 0.f : 1.f - t);
            xw1 = (fF < 0.f) ? 0.f : ((fF > 0.f) ? 1.f : t);
        }
        {
            float u = ly * 2.f - 0.5f, fF = floorf(u), t = u - fF;
            yw0 = (fF < 0.f) ? 1.f : ((fF > 0.f) ? 0.f : 1.f - t);
            yw1 = (fF < 0.f) ? 0.f : ((fF > 0.f) ? 1.f : t);
        }
        {
            float u = lz * 2.f - 0.5f, fF = floorf(u), t = u - fF;
            zw0 = (fF < 0.f) ? 1.f : ((fF > 0.f) ? 0.f : 1.f - t);
            zw1 = (fF < 0.f) ? 0.f : ((fF > 0.f) ? 1.f : t);
        }
        xw0 *= maskf; xw1 *= maskf;          // fold mask: W=0 => sigma=0, rgb pre-act=0
        float g0 = yw0 * zw0, g1 = yw0 * zw1, g2 = yw1 * zw0, g3 = yw1 * zw1;
        WtU[       s] = pkh(xw0 * g0, xw1 * g0);
        WtU[ 776 + s] = pkh(xw0 * g1, xw1 * g1);
        WtU[1552 + s] = pkh(xw0 * g2, xw1 * g2);
        WtU[2328 + s] = pkh(xw0 * g3, xw1 * g3);
        clinL[s] = clin;
    };

    // ---- wave-local geometry over [w*seg, (w+1)*seg) — all waves balanced ----
    if (lane < seg)      geom(w * seg + lane);
    if (lane + 64 < seg) geom(w * seg + 64 + lane);

    // ---- tile-0 coeff gather issues now; latency hides under B'' build ----
    // (clinL read is wave-local: same wave wrote it; compiler inserts lgkmcnt)
    const float4* g4 = (const float4*)grid;
    float4 cv0 = {0,0,0,0}, cv1 = {0,0,0,0}, cv2 = {0,0,0,0}, cv3 = {0,0,0,0};
    if (nT > 0) {
        int clinC = clinL[w * seg + m];
        const float4* gp = g4 + (clinC << 4) + (quad << 2);
        cv0 = gp[0]; cv1 = gp[1]; cv2 = gp[2]; cv3 = gp[3];
    }

    // ---- build B'': one (f,a) entry per thread; cols 4f+c (c<3 SH-contracted, c=3 sigma) ----
    {
        float shm[9];
        float inv = 1.0f / dnorm;
        float nx = dx * inv, ny = dy * inv, nz = dz * inv;
        shm[0] = 0.28209479177387814f;
        shm[1] = -0.4886025119029199f * ny;
        shm[2] = 0.4886025119029199f * nz;
        shm[3] = -0.4886025119029199f * nx;
        shm[4] = 1.0925484305920792f * nx * ny;
        shm[5] = -1.0925484305920792f * ny * nz;
        shm[6] = 0.31539156525252005f * (2.f * nz * nz - nx * nx - ny * ny);
        shm[7] = -1.0925484305920792f * nx * nz;
        shm[8] = 0.5462742152960396f * (nx * nx - ny * ny);

        const float* base = atoms + tid * 28;
        float4 v0 = *(const float4*)(base);
        float4 v1 = *(const float4*)(base + 4);
        float4 v2 = *(const float4*)(base + 8);
        float4 v3 = *(const float4*)(base + 12);
        float4 v4 = *(const float4*)(base + 16);
        float4 v5 = *(const float4*)(base + 20);
        float4 v6 = *(const float4*)(base + 24);

        float s0 = v0.x*shm[0] + v0.y*shm[1] + v0.z*shm[2] + v0.w*shm[3]
                 + v1.x*shm[4] + v1.y*shm[5] + v1.z*shm[6] + v1.w*shm[7] + v2.x*shm[8];
        float s1 = v2.y*shm[0] + v2.z*shm[1] + v2.w*shm[2] + v3.x*shm[3]
                 + v3.y*shm[4] + v3.z*shm[5] + v3.w*shm[6] + v4.x*shm[7] + v4.y*shm[8];
        float s2 = v4.z*shm[0] + v4.w*shm[1] + v5.x*shm[2] + v5.y*shm[3]
                 + v5.z*shm[4] + v5.w*shm[5] + v6.x*shm[6] + v6.y*shm[7] + v6.z*shm[8];

        int f = tid >> 6, a = tid & 63;
        int cb = (f << 2) * 72 + a;          // row (4f+c), stride 72
        BpL[cb]        = __float2bfloat16(s0);
        BpL[cb + 72]   = __float2bfloat16(s1);
        BpL[cb + 144]  = __float2bfloat16(s2);
        BpL[cb + 216]  = __float2bfloat16(v6.w);   // sigma column
    }
    __syncthreads();

    // ---- B-fragments (tile-invariant); padded stride -> 2-way banks (free) ----
    short8 bq00, bq01, bq10, bq11;
    {
        const short* bs = (const short*)BpL;
        const short* p0 = bs + m * 72 + (quad << 4);
        bq00 = *(const short8*)(p0);
        bq01 = *(const short8*)(p0 + 8);
        const short* p1 = bs + (16 + m) * 72 + (quad << 4);
        bq10 = *(const short8*)(p1);
        bq11 = *(const short8*)(p1 + 8);
    }

    float* out_rgb   = out;
    float* out_alpha = out + BATCH * 3;
    float* out_depth = out + BATCH * 3 + BATCH * NSAMP;
    const int f0 = m >> 2;

    // ---- main loop: compile-time 6 bodies, uniform break at nT (2-4 typical) ----
    #pragma unroll
    for (int t = 0; t < 6; ++t) {
        if (t >= nT) break;

        // A-frags: raw coeff, bf16
        union { unsigned u[4]; short8 s; } a0p, a1p;
        a0p.u[0] = pkbf(cv0.x, cv0.y); a0p.u[1] = pkbf(cv0.z, cv0.w);
        a0p.u[2] = pkbf(cv1.x, cv1.y); a0p.u[3] = pkbf(cv1.z, cv1.w);
        a1p.u[0] = pkbf(cv2.x, cv2.y); a1p.u[1] = pkbf(cv2.z, cv2.w);
        a1p.u[2] = pkbf(cv3.x, cv3.y); a1p.u[3] = pkbf(cv3.z, cv3.w);

        // prefetch next tile's coeff gather (clin from LDS, wave-local)
        if (t + 1 < nT) {
            int clinC = clinL[w * seg + ((t + 1) << 4) + m];
            const float4* gp = g4 + (clinC << 4) + (quad << 2);
            cv0 = gp[0]; cv1 = gp[1]; cv2 = gp[2]; cv3 = gp[3];
        }

        // stage 1: proj = Coeff(16x64) x B''(64x32)
        floatx4 acc0 = {0.f, 0.f, 0.f, 0.f};
        floatx4 acc1 = {0.f, 0.f, 0.f, 0.f};
        acc0 = __builtin_amdgcn_mfma_f32_16x16x32_bf16(a0p.s, bq00, acc0, 0, 0, 0);
        acc0 = __builtin_amdgcn_mfma_f32_16x16x32_bf16(a1p.s, bq01, acc0, 0, 0, 0);
        acc1 = __builtin_amdgcn_mfma_f32_16x16x32_bf16(a0p.s, bq10, acc1, 0, 0, 0);
        acc1 = __builtin_amdgcn_mfma_f32_16x16x32_bf16(a1p.s, bq11, acc1, 0, 0, 0);

        // stage 2: p[s][c] = sum_f W[s][f]*proj[s][4f+c]; activations fused here
        int sb = w * seg + (t << 4) + (quad << 2);
        union { uintx4 v; unsigned u[4]; } wt;
        wt.v = *(const uintx4*)&WtU[f0 * 776 + sb];   // one ds_read_b128, 2-way banks
        #pragma unroll
        for (int r = 0; r < 4; ++r) {
            float2 wab = uph(wt.u[r]);
            float p = wab.x * acc0[r] + wab.y * acc1[r];
            p = coset4_sum(p);                        // reduce over f; c = m&3
            if (m < 4) {                              // lane m holds channel c=m
                float e = __expf((m == 3) ? (-fmaxf(p, 0.f) * dist) : -p);
                float v = (m == 3) ? (1.f - e) : (1.f / (1.f + e));
                pAct[((sb + r) << 2) + m] = v;        // {r,g,b,a}
            }
        }
    }

    __syncthreads();

    // ---- phase 2: transmittance scan + composite (transcendental-free) ----
    {
        const int sLim = seg << 3;          // samples with pAct written; beyond -> a=0
        const bool act = (tid < 384);
        const int s0 = tid * 2;             // 0..766
        float a0 = 0.f, a1 = 0.f;
        float r0 = 0.f, g0c = 0.f, b0c = 0.f, r1 = 0.f, g1c = 0.f, b1c = 0.f;
        if (act) {
            if (s0 < sLim) {
                float4 q = *(const float4*)&pAct[s0 << 2];
                r0 = q.x; g0c = q.y; b0c = q.z; a0 = q.w;
            }
            if (s0 + 1 < sLim) {
                float4 q = *(const float4*)&pAct[(s0 + 1) << 2];
                r1 = q.x; g1c = q.y; b1c = q.z; a1 = q.w;
            }
            // coalesced alpha store (zeros beyond the clipped range included)
            out_alpha[ray * NSAMP + s0] = a0;
            if (s0 + 1 < NSAMP) out_alpha[ray * NSAMP + s0 + 1] = a1;
        }
        float pr = (1.f - a0 + 1e-10f) * (1.f - a1 + 1e-10f);

        // intra-wave inclusive multiplicative scan over pair products
        float incl = pr;
        #pragma unroll
        for (int off = 1; off < 64; off <<= 1) {
            float v = __shfl_up(incl, off, 64);
            if (lane >= off) incl *= v;
        }
        if (lane == 63) wprodL[w] = incl;
        __syncthreads();

        float base = 1.f;
        #pragma unroll
        for (int ww = 0; ww < 5; ++ww)
            if (w > ww) base *= wprodL[ww];
        float excl = __shfl_up(incl, 1, 64);
        if (lane == 0) excl = 1.f;
        float trans = base * excl;

        float c0 = 0.f, c1 = 0.f, c2 = 0.f, accw = 0.f, dep = 0.f;
        if (act) {
            float w0 = a0 * trans;
            c0 += w0 * r0; c1 += w0 * g0c; c2 += w0 * b0c;
            accw += w0;
            dep += w0 * (start + (float)s0 * STEPF);
            trans *= (1.f - a0 + 1e-10f);
            float w1 = a1 * trans;
            c0 += w1 * r1; c1 += w1 * g1c; c2 += w1 * b1c;
            accw += w1;
            dep += w1 * (start + (float)(s0 + 1) * STEPF);
        }
        #pragma unroll
        for (int off = 1; off < 64; off <<= 1) {
            c0   += __shfl_xor(c0, off, 64);
            c1   += __shfl_xor(c1, off, 64);
            c2   += __shfl_xor(c2, off, 64);
            accw += __shfl_xor(accw, off, 64);
            dep  += __shfl_xor(dep, off, 64);
        }
        if (lane == 0) {
            partL[w][0] = c0; partL[w][1] = c1; partL[w][2] = c2;
            partL[w][3] = accw; partL[w][4] = dep;
        }
        __syncthreads();
        if (tid == 0) {
            float C0 = 0.f, C1 = 0.f, C2 = 0.f, AC = 0.f, DP = 0.f;
            #pragma unroll
            for (int ww = 0; ww < 6; ++ww) {   // act threads live in waves 0..5
                C0 += partL[ww][0]; C1 += partL[ww][1]; C2 += partL[ww][2];
                AC += partL[ww][3]; DP += partL[ww][4];
            }
            float bg = 1.f - AC;
            out_rgb[ray * 3 + 0] = C0 + bg;
            out_rgb[ray * 3 + 1] = C1 + bg;
            out_rgb[ray * 3 + 2] = C2 + bg;
            out_depth[ray] = DP;
        }
    }
}

extern "C" void kernel_launch(void* const* d_in, const int* in_sizes, int n_in,
                              void* d_out, int out_size, void* d_ws, size_t ws_size,
                              hipStream_t stream) {
    const float* rays_o = (const float*)d_in[0];
    const float* rays_d = (const float*)d_in[1];
    const float* grid   = (const float*)d_in[2];
    const float* atoms  = (const float*)d_in[3];
    float* out = (float*)d_out;
    hipLaunchKernelGGL(plenoxels_fwd, dim3(BATCH), dim3(512), 0, stream,
                       rays_o, rays_d, grid, atoms, out);
}